// Round 1
// 273.028 us; speedup vs baseline: 1.0324x; 1.0324x over previous
//
#include <hip/hip_runtime.h>

// out[b, d, l] = (x[l, b] < 20 ? embed_w[x[l, b], d] : 0) * sqrt(8)
// Shapes: x (L=2048, B=16) int32; embed_w (50257, 1024) fp32; out (16, 1024, 2048) fp32.
//
// R3 structure: the output is 128 MiB and ~99.96% zeros (tokens uniform in
// [0, 50257), live < 20 -> E[live tokens] ~= 13 of 32768). The previous
// single-kernel version spent ~35 us doing its own zero-fill at ~3.8 TB/s
// (token-gather latency + strided store stream). The rocclr fill kernel is
// measured at 6.6 TB/s in this harness (823 MB / 123 us), so:
//   phase 1: hipMemsetAsync(out, 0)            -> ~20 us at fill BW
//   phase 2: scatter kernel for live rows only -> ~<5 us (13 rows * 4 KB)
//
// Phase 2: one thread per (l, b) token, coalesced x load, per-wave ballot;
// all 64 lanes cooperate on each live row: coalesced 256 B reads of w,
// 4 B stores at 8 KB stride (uncoalesced, but only ~13 KB total stores).

constexpr int D_MODEL = 1024;
constexpr int SEQ_LEN = 2048;
constexpr int BATCH   = 16;
constexpr int MAXTOK  = 20;
__device__ constexpr float SCALE = 2.8284271247461903f; // sqrt(8)

__global__ __launch_bounds__(256) void embed_scatter_kernel(
    const int* __restrict__ x,
    const float* __restrict__ w,
    float* __restrict__ out)
{
    const int idx  = blockIdx.x * 256 + threadIdx.x;   // 0..32767 == l*BATCH + b
    const int lane = threadIdx.x & 63;

    const int tok   = x[idx];                          // fully coalesced
    const bool live = tok < MAXTOK;

    unsigned long long m = __ballot(live);             // wave-uniform
    while (m) {
        const int src = __ffsll(m) - 1;
        m &= m - 1;
        // Broadcast the live lane's token and position to the whole wave.
        const int t  = __shfl(tok, src);
        const int si = __shfl(idx, src);
        const int l  = si >> 4;                        // idx = l*16 + b
        const int b  = si & (BATCH - 1);

        const float* wp = w + (size_t)t * D_MODEL;     // coalesced row read
        float* op = out + (size_t)b * D_MODEL * SEQ_LEN + l;
        #pragma unroll
        for (int k = 0; k < D_MODEL / 64; ++k) {       // 16 iters: d = k*64+lane
            const int d = k * 64 + lane;
            op[(size_t)d * SEQ_LEN] = wp[d] * SCALE;   // 4 B store, 8 KB stride
        }
    }
}

extern "C" void kernel_launch(void* const* d_in, const int* in_sizes, int n_in,
                              void* d_out, int out_size, void* d_ws, size_t ws_size,
                              hipStream_t stream) {
    const int*   x = (const int*)d_in[0];     // (2048, 16) token ids
    const float* w = (const float*)d_in[1];   // (50257, 1024)
    float*     out = (float*)d_out;           // (16, 1024, 2048)

    // Phase 1: zero the whole output at rocclr-fill bandwidth (~6.6 TB/s).
    hipMemsetAsync(out, 0, (size_t)BATCH * D_MODEL * SEQ_LEN * sizeof(float), stream);

    // Phase 2: overwrite the ~13 live columns.
    const int total = SEQ_LEN * BATCH;                 // 32768 tokens
    dim3 grid(total / 256);                            // 128 blocks
    dim3 block(256);
    embed_scatter_kernel<<<grid, block, 0, stream>>>(x, w, out);
}